// Round 1
// baseline (1827.032 us; speedup 1.0000x reference)
//
#include <hip/hip_runtime.h>

#define NG 1024
#define GN_EPS 1e-5f

// ---------------- graph boundaries from sorted batch ----------------
__global__ void k_bounds(const int* __restrict__ batch, int* __restrict__ goff, int N) {
  int i = blockIdx.x * blockDim.x + threadIdx.x;
  if (i >= N) return;
  int b = batch[i];
  int pb = (i == 0) ? -1 : batch[i - 1];
  for (int g = pb + 1; g <= b; ++g) goff[g] = i;
  if (i == N - 1) {
    for (int g = b + 1; g <= NG; ++g) goff[g] = N;
  }
}

// ---------------- CSR build ----------------
__global__ void k_degcount(const int* __restrict__ dst, int* __restrict__ deg, int E) {
  int e = blockIdx.x * blockDim.x + threadIdx.x;
  if (e < E) atomicAdd(&deg[dst[e]], 1);
}

__global__ void k_scan_a(const int* deg, int* csum, int N) {
  __shared__ int lds[1024];
  int t = threadIdx.x;
  int idx = blockIdx.x * 1024 + t;
  lds[t] = (idx < N) ? deg[idx] : 0;
  __syncthreads();
  for (int off = 512; off > 0; off >>= 1) {
    if (t < off) lds[t] += lds[t + off];
    __syncthreads();
  }
  if (t == 0) csum[blockIdx.x] = lds[0];
}

__global__ void k_scan_b(int* csum, int* rowptrN, int nblk) {
  __shared__ int lds[128];
  int t = threadIdx.x;
  int v = (t < nblk) ? csum[t] : 0;
  lds[t] = v;
  __syncthreads();
  for (int off = 1; off < 128; off <<= 1) {
    int u = (t >= off) ? lds[t - off] : 0;
    __syncthreads();
    lds[t] += u;
    __syncthreads();
  }
  if (t < nblk) csum[t] = lds[t] - v;  // exclusive chunk offsets
  if (t == 127) *rowptrN = lds[127];   // total = E
}

__global__ void k_scan_c(const int* deg, const int* csum,
                         int* rowptr, int* cursor, int N) {
  __shared__ int lds[1024];
  int t = threadIdx.x;
  int idx = blockIdx.x * 1024 + t;
  int v = (idx < N) ? deg[idx] : 0;
  lds[t] = v;
  __syncthreads();
  for (int off = 1; off < 1024; off <<= 1) {
    int u = (t >= off) ? lds[t - off] : 0;
    __syncthreads();
    lds[t] += u;
    __syncthreads();
  }
  if (idx < N) {
    int rp = lds[t] - v + csum[blockIdx.x];
    rowptr[idx] = rp;
    cursor[idx] = rp;
  }
}

__global__ void k_csrfill(const int* __restrict__ src, const int* __restrict__ dst,
                          int* cursor, int* __restrict__ col, int E) {
  int e = blockIdx.x * blockDim.x + threadIdx.x;
  if (e < E) {
    int p = atomicAdd(&cursor[dst[e]], 1);
    col[p] = src[e];
  }
}

// ---------------- GraphNorm (one block per graph, segment contiguous) ----------------
template <int F>
__global__ void k_gn(const float* x, float* out, const int* __restrict__ goff,
                     const float* __restrict__ w, const float* __restrict__ b,
                     const float* __restrict__ ms) {
  constexpr int NPW = 256 / F;
  __shared__ float r1[256], r2[256];
  __shared__ float sA[F], sB[F];
  int g = blockIdx.x;
  int s = goff[g], e = goff[g + 1];
  int t = threadIdx.x;
  int f = t % F, sub = t / F;
  float s1 = 0.f, s2 = 0.f;
  for (int i = s + sub; i < e; i += NPW) {
    float v = x[i * F + f];
    s1 += v;
    s2 += v * v;
  }
  r1[t] = s1;
  r2[t] = s2;
  __syncthreads();
  if (t < F) {
    float S1 = 0.f, S2 = 0.f;
    for (int k = 0; k < NPW; ++k) {
      S1 += r1[k * F + t];
      S2 += r2[k * F + t];
    }
    float cnt = (float)max(e - s, 1);
    float mean = S1 / cnt, m2 = S2 / cnt;
    float m = ms[t];
    float var = m2 + mean * mean * m * (m - 2.f);  // E[(x-mean*ms)^2]
    float rsq = rsqrtf(var + GN_EPS);
    float Av = w[t] * rsq;
    sA[t] = Av;
    sB[t] = b[t] - mean * m * Av;
  }
  __syncthreads();
  float Af = sA[f], Bf = sB[f];
  for (int i = s + sub; i < e; i += NPW) {
    out[i * F + f] = x[i * F + f] * Af + Bf;
  }
}

// ---------------- GraphConv: gather(CSR) + relu(W_rel*agg + W_root*h + b) ----------------
// block = 256 (4 waves). Each block owns a 64-node tile.
// gather: wave w fills LDS rows [16w,16w+16). matvec: lane = node, wave w computes
// output features [16w,16w+16) with weights delivered via SGPR (wave-uniform index).
template <int FIN>
__global__ __launch_bounds__(256) void k_conv(
    const float* __restrict__ hin, float* __restrict__ hout,
    const int* __restrict__ rowptr, const int* __restrict__ col,
    const float* __restrict__ wrel, const float* __restrict__ brel,
    const float* __restrict__ wroot, int N) {
  constexpr int PAD = FIN + 4;
  __shared__ float aggL[64 * PAD];
  __shared__ float hL[64 * PAD];
  int tile = blockIdx.x;
  int lane = threadIdx.x & 63;
  int w = __builtin_amdgcn_readfirstlane(threadIdx.x >> 6);

  if (FIN == 64) {
    for (int nl = 0; nl < 16; ++nl) {
      int r = w * 16 + nl;
      int n = tile * 64 + r;
      float a = 0.f, hv = 0.f;
      if (n < N) {
        int s = rowptr[n], e = rowptr[n + 1];
        for (int k = s; k < e; ++k) {
          int nb = col[k];
          a += hin[nb * 64 + lane];
        }
        hv = hin[n * 64 + lane];
      }
      aggL[r * PAD + lane] = a;
      hL[r * PAD + lane] = hv;
    }
  } else {
    // FIN == 16: 4 nodes in flight per pass, lane = sub*16+f
    int f = lane & 15, sub = lane >> 4;
    for (int c = 0; c < 4; ++c) {
      int r = w * 16 + c * 4 + sub;
      int n = tile * 64 + r;
      float a = 0.f, hv = 0.f;
      if (n < N) {
        int s = rowptr[n], e = rowptr[n + 1];
        for (int k = s; k < e; ++k) {
          int nb = col[k];
          a += hin[nb * 16 + f];
        }
        hv = hin[n * 16 + f];
      }
      aggL[r * PAD + f] = a;
      hL[r * PAD + f] = hv;
    }
  }
  __syncthreads();

  int wbase = w * 16;
  float accR[16], accT[16];
#pragma unroll
  for (int j = 0; j < 16; ++j) {
    accR[j] = 0.f;
    accT[j] = 0.f;
  }
#pragma unroll 2
  for (int fq = 0; fq < FIN / 4; ++fq) {
    float4 qa = *(const float4*)&aggL[lane * PAD + fq * 4];
    float4 qh = *(const float4*)&hL[lane * PAD + fq * 4];
#pragma unroll
    for (int j = 0; j < 16; ++j) {
      int o = wbase + j;
      const float* wr = &wrel[o * FIN + fq * 4];
      const float* wt = &wroot[o * FIN + fq * 4];
      accR[j] += wr[0] * qa.x + wr[1] * qa.y + wr[2] * qa.z + wr[3] * qa.w;
      accT[j] += wt[0] * qh.x + wt[1] * qh.y + wt[2] * qh.z + wt[3] * qh.w;
    }
  }
  int n = tile * 64 + lane;
  if (n < N) {
#pragma unroll
    for (int q = 0; q < 4; ++q) {
      float4 rv;
      float* rr = (float*)&rv;
#pragma unroll
      for (int jj = 0; jj < 4; ++jj) {
        int j = q * 4 + jj;
        float v = accR[j] + accT[j] + brel[wbase + j];
        rr[jj] = fmaxf(v, 0.f);
      }
      *(float4*)&hout[n * 64 + wbase + q * 4] = rv;
    }
  }
}

// ---------------- mean-pool + dense(relu) + out + softmax ----------------
__global__ void k_final(const float* __restrict__ h, const int* __restrict__ goff,
                        const float* __restrict__ dw, const float* __restrict__ db,
                        const float* __restrict__ ow, const float* __restrict__ ob,
                        float* __restrict__ out) {
  __shared__ float red[256];
  __shared__ float pl[64];
  __shared__ float gl[64];
  int g = blockIdx.x;
  int s = goff[g], e = goff[g + 1];
  int t = threadIdx.x;
  int f = t & 63, sub = t >> 6;
  float s1 = 0.f;
  for (int i = s + sub; i < e; i += 4) s1 += h[i * 64 + f];
  red[t] = s1;
  __syncthreads();
  if (t < 64) {
    float S = red[t] + red[64 + t] + red[128 + t] + red[192 + t];
    float cnt = (float)max(e - s, 1);
    pl[t] = S / cnt;
  }
  __syncthreads();
  if (t < 64) {
    float acc = db[t];
#pragma unroll 8
    for (int k = 0; k < 64; ++k) acc += dw[t * 64 + k] * pl[k];
    gl[t] = fmaxf(acc, 0.f);
  }
  __syncthreads();
  if (t == 0) {
    float l0 = ob[0], l1 = ob[1];
    for (int k = 0; k < 64; ++k) {
      l0 += ow[k] * gl[k];
      l1 += ow[64 + k] * gl[k];
    }
    float m = fmaxf(l0, l1);
    float e0 = expf(l0 - m), e1 = expf(l1 - m);
    float inv = 1.f / (e0 + e1);
    out[g * 2 + 0] = e0 * inv;
    out[g * 2 + 1] = e1 * inv;
  }
}

extern "C" void kernel_launch(void* const* d_in, const int* in_sizes, int n_in,
                              void* d_out, int out_size, void* d_ws, size_t ws_size,
                              hipStream_t stream) {
  const float* x = (const float*)d_in[0];
  const int* ei = (const int*)d_in[1];
  const int* batch = (const int*)d_in[2];
  const float* gn0_w = (const float*)d_in[3];
  const float* gn0_b = (const float*)d_in[4];
  const float* gn0_ms = (const float*)d_in[5];
  const float* gn1_w = (const float*)d_in[6];
  const float* gn1_b = (const float*)d_in[7];
  const float* gn1_ms = (const float*)d_in[8];
  const float* gn2_w = (const float*)d_in[9];
  const float* gn2_b = (const float*)d_in[10];
  const float* gn2_ms = (const float*)d_in[11];
  const float* w1_rel = (const float*)d_in[12];
  const float* b1 = (const float*)d_in[13];
  const float* w1_root = (const float*)d_in[14];
  const float* w2_rel = (const float*)d_in[15];
  const float* b2 = (const float*)d_in[16];
  const float* w2_root = (const float*)d_in[17];
  const float* w3_rel = (const float*)d_in[18];
  const float* b3 = (const float*)d_in[19];
  const float* w3_root = (const float*)d_in[20];
  const float* dense_w = (const float*)d_in[21];
  const float* dense_b = (const float*)d_in[22];
  const float* out_w = (const float*)d_in[23];
  const float* out_b = (const float*)d_in[24];

  int N = in_sizes[2];
  int E = in_sizes[1] / 2;

  char* ws = (char*)d_ws;
  auto alloc = [&](size_t bytes) {
    char* p = ws;
    ws += (bytes + 255) & ~(size_t)255;
    return p;
  };
  int* rowptr = (int*)alloc(((size_t)N + 1) * 4);
  int* cursor = (int*)alloc((size_t)N * 4);  // doubles as deg during count
  int* csum = (int*)alloc(512);
  int* goff = (int*)alloc((NG + 1) * 4);
  int* col = (int*)alloc((size_t)E * 4);
  float* hA = (float*)alloc((size_t)N * 64 * 4);
  float* hB = (float*)alloc((size_t)N * 64 * 4);

  hipMemsetAsync(cursor, 0, (size_t)N * 4, stream);
  k_bounds<<<(N + 255) / 256, 256, 0, stream>>>(batch, goff, N);
  k_degcount<<<(E + 255) / 256, 256, 0, stream>>>(ei + E, cursor, E);
  int nblk = (N + 1023) / 1024;
  k_scan_a<<<nblk, 1024, 0, stream>>>(cursor, csum, N);
  k_scan_b<<<1, 128, 0, stream>>>(csum, rowptr + N, nblk);
  k_scan_c<<<nblk, 1024, 0, stream>>>(cursor, csum, rowptr, cursor, N);
  k_csrfill<<<(E + 255) / 256, 256, 0, stream>>>(ei, ei + E, cursor, col, E);

  int tiles = (N + 63) / 64;
  k_gn<16><<<NG, 256, 0, stream>>>(x, hA, goff, gn0_w, gn0_b, gn0_ms);
  k_conv<16><<<tiles, 256, 0, stream>>>(hA, hB, rowptr, col, w1_rel, b1, w1_root, N);
  k_gn<64><<<NG, 256, 0, stream>>>(hB, hB, goff, gn1_w, gn1_b, gn1_ms);
  k_conv<64><<<tiles, 256, 0, stream>>>(hB, hA, rowptr, col, w2_rel, b2, w2_root, N);
  k_gn<64><<<NG, 256, 0, stream>>>(hA, hA, goff, gn2_w, gn2_b, gn2_ms);
  k_conv<64><<<tiles, 256, 0, stream>>>(hA, hB, rowptr, col, w3_rel, b3, w3_root, N);
  k_final<<<NG, 256, 0, stream>>>(hB, goff, dense_w, dense_b, out_w, out_b, (float*)d_out);
}

// Round 2
// 951.588 us; speedup vs baseline: 1.9200x; 1.9200x over previous
//
#include <hip/hip_runtime.h>

#define NG 1024
#define GN_EPS 1e-5f

__device__ __forceinline__ void f4acc(float4& a, const float4 b) {
  a.x += b.x; a.y += b.y; a.z += b.z; a.w += b.w;
}
__device__ __forceinline__ void f4red(float4& a, int mask) {
  a.x += __shfl_xor(a.x, mask);
  a.y += __shfl_xor(a.y, mask);
  a.z += __shfl_xor(a.z, mask);
  a.w += __shfl_xor(a.w, mask);
}

// ---------------- graph boundaries from sorted batch ----------------
__global__ void k_bounds(const int* __restrict__ batch, int* __restrict__ goff, int N) {
  int i = blockIdx.x * blockDim.x + threadIdx.x;
  if (i >= N) return;
  int b = batch[i];
  int pb = (i == 0) ? -1 : batch[i - 1];
  for (int g = pb + 1; g <= b; ++g) goff[g] = i;
  if (i == N - 1) {
    for (int g = b + 1; g <= NG; ++g) goff[g] = N;
  }
}

// ---------------- CSR build ----------------
__global__ void k_degcount(const int* __restrict__ dst, int* __restrict__ deg, int E) {
  int e = blockIdx.x * blockDim.x + threadIdx.x;
  if (e < E) atomicAdd(&deg[dst[e]], 1);
}

__global__ void k_scan_a(const int* deg, int* csum, int N) {
  __shared__ int lds[1024];
  int t = threadIdx.x;
  int idx = blockIdx.x * 1024 + t;
  lds[t] = (idx < N) ? deg[idx] : 0;
  __syncthreads();
  for (int off = 512; off > 0; off >>= 1) {
    if (t < off) lds[t] += lds[t + off];
    __syncthreads();
  }
  if (t == 0) csum[blockIdx.x] = lds[0];
}

__global__ void k_scan_b(int* csum, int* rowptrN, int nblk) {
  __shared__ int lds[128];
  int t = threadIdx.x;
  int v = (t < nblk) ? csum[t] : 0;
  lds[t] = v;
  __syncthreads();
  for (int off = 1; off < 128; off <<= 1) {
    int u = (t >= off) ? lds[t - off] : 0;
    __syncthreads();
    lds[t] += u;
    __syncthreads();
  }
  if (t < nblk) csum[t] = lds[t] - v;  // exclusive chunk offsets
  if (t == 127) *rowptrN = lds[127];   // total = E
}

__global__ void k_scan_c(const int* deg, const int* csum,
                         int* rowptr, int* cursor, int N) {
  __shared__ int lds[1024];
  int t = threadIdx.x;
  int idx = blockIdx.x * 1024 + t;
  int v = (idx < N) ? deg[idx] : 0;
  lds[t] = v;
  __syncthreads();
  for (int off = 1; off < 1024; off <<= 1) {
    int u = (t >= off) ? lds[t - off] : 0;
    __syncthreads();
    lds[t] += u;
    __syncthreads();
  }
  if (idx < N) {
    int rp = lds[t] - v + csum[blockIdx.x];
    rowptr[idx] = rp;
    cursor[idx] = rp;
  }
}

__global__ void k_csrfill(const int* __restrict__ src, const int* __restrict__ dst,
                          int* cursor, int* __restrict__ col, int E) {
  int e = blockIdx.x * blockDim.x + threadIdx.x;
  if (e < E) {
    int p = atomicAdd(&cursor[dst[e]], 1);
    col[p] = src[e];
  }
}

// ---------------- GraphNorm (one block per graph, segment contiguous) ----------------
template <int F>
__global__ void k_gn(const float* x, float* out, const int* __restrict__ goff,
                     const float* __restrict__ w, const float* __restrict__ b,
                     const float* __restrict__ ms) {
  constexpr int NPW = 256 / F;
  __shared__ float r1[256], r2[256];
  __shared__ float sA[F], sB[F];
  int g = blockIdx.x;
  int s = goff[g], e = goff[g + 1];
  int t = threadIdx.x;
  int f = t % F, sub = t / F;
  float s1 = 0.f, s2 = 0.f;
  for (int i = s + sub; i < e; i += NPW) {
    float v = x[i * F + f];
    s1 += v;
    s2 += v * v;
  }
  r1[t] = s1;
  r2[t] = s2;
  __syncthreads();
  if (t < F) {
    float S1 = 0.f, S2 = 0.f;
    for (int k = 0; k < NPW; ++k) {
      S1 += r1[k * F + t];
      S2 += r2[k * F + t];
    }
    float cnt = (float)max(e - s, 1);
    float mean = S1 / cnt, m2 = S2 / cnt;
    float m = ms[t];
    float var = m2 + mean * mean * m * (m - 2.f);  // E[(x-mean*ms)^2]
    float rsq = rsqrtf(var + GN_EPS);
    float Av = w[t] * rsq;
    sA[t] = Av;
    sB[t] = b[t] - mean * m * Av;
  }
  __syncthreads();
  float Af = sA[f], Bf = sB[f];
  for (int i = s + sub; i < e; i += NPW) {
    out[i * F + f] = x[i * F + f] * Af + Bf;
  }
}

// ---------------- GraphConv: gather(CSR) + relu(W_rel*agg + W_root*h + b) ----------------
// block = 256 (4 waves), tile = 64 nodes.
// Gather phase: wave w owns rows [16w,16w+16). Within a row, lane = (slot, fquad):
//   FIN=64: 4 neighbor-slots x 16 float4-quads; FIN=16: 16 slots x 4 quads.
//   Unroll-by-2 dual accumulators -> 8 gathers in flight/wave. shfl_xor slot-reduce.
// Matvec phase: lane = node, wave w computes output features [16w,16w+16);
//   weights via wave-uniform (SGPR) loads, agg via conflict-free ds_read_b128,
//   root term straight from global (L2-hot).
template <int FIN>
__global__ __launch_bounds__(256) void k_conv(
    const float* __restrict__ hin, float* __restrict__ hout,
    const int* __restrict__ rowptr, const int* __restrict__ col,
    const float* __restrict__ wrel, const float* __restrict__ brel,
    const float* __restrict__ wroot, int N) {
  constexpr int PAD = FIN + 4;             // 68 or 20 words: lane*PAD walks all 32 banks / 8 lanes
  constexpr int NSLOT = (FIN == 64) ? 4 : 16;
  __shared__ float aggL[64 * PAD];
  int tile = blockIdx.x;
  int lane = threadIdx.x & 63;
  int w = __builtin_amdgcn_readfirstlane(threadIdx.x >> 6);

  int q = (FIN == 64) ? (lane & 15) : (lane & 3);   // float4 quad
  int slot = (FIN == 64) ? (lane >> 4) : (lane >> 2);

  for (int nl = 0; nl < 16; ++nl) {
    int r = w * 16 + nl;
    int n = tile * 64 + r;
    float4 a0 = make_float4(0.f, 0.f, 0.f, 0.f);
    float4 a1 = make_float4(0.f, 0.f, 0.f, 0.f);
    if (n < N) {
      int s = rowptr[n], e = rowptr[n + 1];
      int k = s + slot;
      for (; k + NSLOT < e; k += 2 * NSLOT) {
        int nb0 = col[k];
        int nb1 = col[k + NSLOT];
        float4 v0 = *(const float4*)&hin[(size_t)nb0 * FIN + q * 4];
        float4 v1 = *(const float4*)&hin[(size_t)nb1 * FIN + q * 4];
        f4acc(a0, v0);
        f4acc(a1, v1);
      }
      if (k < e) {
        int nb = col[k];
        float4 v = *(const float4*)&hin[(size_t)nb * FIN + q * 4];
        f4acc(a0, v);
      }
    }
    f4acc(a0, a1);
    // reduce across neighbor slots
    if (FIN == 64) {
      f4red(a0, 16);
      f4red(a0, 32);
      if (slot == 0) *(float4*)&aggL[r * PAD + q * 4] = a0;
    } else {
      f4red(a0, 4);
      f4red(a0, 8);
      f4red(a0, 16);
      f4red(a0, 32);
      if (slot == 0) *(float4*)&aggL[r * PAD + q * 4] = a0;
    }
  }
  __syncthreads();

  int n = tile * 64 + lane;
  if (n >= N) return;
  int wbase = w * 16;
  float accR[16], accT[16];
#pragma unroll
  for (int j = 0; j < 16; ++j) {
    accR[j] = 0.f;
    accT[j] = 0.f;
  }
#pragma unroll 2
  for (int fq = 0; fq < FIN / 4; ++fq) {
    float4 qa = *(const float4*)&aggL[lane * PAD + fq * 4];
    float4 qh = *(const float4*)&hin[(size_t)n * FIN + fq * 4];
#pragma unroll
    for (int j = 0; j < 16; ++j) {
      int o = wbase + j;
      const float* wr = &wrel[o * FIN + fq * 4];
      const float* wt = &wroot[o * FIN + fq * 4];
      accR[j] += wr[0] * qa.x + wr[1] * qa.y + wr[2] * qa.z + wr[3] * qa.w;
      accT[j] += wt[0] * qh.x + wt[1] * qh.y + wt[2] * qh.z + wt[3] * qh.w;
    }
  }
#pragma unroll
  for (int qq = 0; qq < 4; ++qq) {
    float4 rv;
    float* rr = (float*)&rv;
#pragma unroll
    for (int jj = 0; jj < 4; ++jj) {
      int j = qq * 4 + jj;
      float v = accR[j] + accT[j] + brel[wbase + j];
      rr[jj] = fmaxf(v, 0.f);
    }
    *(float4*)&hout[(size_t)n * 64 + wbase + qq * 4] = rv;
  }
}

// ---------------- mean-pool + dense(relu) + out + softmax ----------------
__global__ void k_final(const float* __restrict__ h, const int* __restrict__ goff,
                        const float* __restrict__ dw, const float* __restrict__ db,
                        const float* __restrict__ ow, const float* __restrict__ ob,
                        float* __restrict__ out) {
  __shared__ float red[256];
  __shared__ float pl[64];
  __shared__ float gl[64];
  int g = blockIdx.x;
  int s = goff[g], e = goff[g + 1];
  int t = threadIdx.x;
  int f = t & 63, sub = t >> 6;
  float s1 = 0.f;
  for (int i = s + sub; i < e; i += 4) s1 += h[i * 64 + f];
  red[t] = s1;
  __syncthreads();
  if (t < 64) {
    float S = red[t] + red[64 + t] + red[128 + t] + red[192 + t];
    float cnt = (float)max(e - s, 1);
    pl[t] = S / cnt;
  }
  __syncthreads();
  if (t < 64) {
    float acc = db[t];
#pragma unroll 8
    for (int k = 0; k < 64; ++k) acc += dw[t * 64 + k] * pl[k];
    gl[t] = fmaxf(acc, 0.f);
  }
  __syncthreads();
  if (t == 0) {
    float l0 = ob[0], l1 = ob[1];
    for (int k = 0; k < 64; ++k) {
      l0 += ow[k] * gl[k];
      l1 += ow[64 + k] * gl[k];
    }
    float m = fmaxf(l0, l1);
    float e0 = expf(l0 - m), e1 = expf(l1 - m);
    float inv = 1.f / (e0 + e1);
    out[g * 2 + 0] = e0 * inv;
    out[g * 2 + 1] = e1 * inv;
  }
}

extern "C" void kernel_launch(void* const* d_in, const int* in_sizes, int n_in,
                              void* d_out, int out_size, void* d_ws, size_t ws_size,
                              hipStream_t stream) {
  const float* x = (const float*)d_in[0];
  const int* ei = (const int*)d_in[1];
  const int* batch = (const int*)d_in[2];
  const float* gn0_w = (const float*)d_in[3];
  const float* gn0_b = (const float*)d_in[4];
  const float* gn0_ms = (const float*)d_in[5];
  const float* gn1_w = (const float*)d_in[6];
  const float* gn1_b = (const float*)d_in[7];
  const float* gn1_ms = (const float*)d_in[8];
  const float* gn2_w = (const float*)d_in[9];
  const float* gn2_b = (const float*)d_in[10];
  const float* gn2_ms = (const float*)d_in[11];
  const float* w1_rel = (const float*)d_in[12];
  const float* b1 = (const float*)d_in[13];
  const float* w1_root = (const float*)d_in[14];
  const float* w2_rel = (const float*)d_in[15];
  const float* b2 = (const float*)d_in[16];
  const float* w2_root = (const float*)d_in[17];
  const float* w3_rel = (const float*)d_in[18];
  const float* b3 = (const float*)d_in[19];
  const float* w3_root = (const float*)d_in[20];
  const float* dense_w = (const float*)d_in[21];
  const float* dense_b = (const float*)d_in[22];
  const float* out_w = (const float*)d_in[23];
  const float* out_b = (const float*)d_in[24];

  int N = in_sizes[2];
  int E = in_sizes[1] / 2;

  char* ws = (char*)d_ws;
  auto alloc = [&](size_t bytes) {
    char* p = ws;
    ws += (bytes + 255) & ~(size_t)255;
    return p;
  };
  int* rowptr = (int*)alloc(((size_t)N + 1) * 4);
  int* cursor = (int*)alloc((size_t)N * 4);  // doubles as deg during count
  int* csum = (int*)alloc(512);
  int* goff = (int*)alloc((NG + 1) * 4);
  int* col = (int*)alloc((size_t)E * 4);
  float* hA = (float*)alloc((size_t)N * 64 * 4);
  float* hB = (float*)alloc((size_t)N * 64 * 4);

  hipMemsetAsync(cursor, 0, (size_t)N * 4, stream);
  k_bounds<<<(N + 255) / 256, 256, 0, stream>>>(batch, goff, N);
  k_degcount<<<(E + 255) / 256, 256, 0, stream>>>(ei + E, cursor, E);
  int nblk = (N + 1023) / 1024;
  k_scan_a<<<nblk, 1024, 0, stream>>>(cursor, csum, N);
  k_scan_b<<<1, 128, 0, stream>>>(csum, rowptr + N, nblk);
  k_scan_c<<<nblk, 1024, 0, stream>>>(cursor, csum, rowptr, cursor, N);
  k_csrfill<<<(E + 255) / 256, 256, 0, stream>>>(ei, ei + E, cursor, col, E);

  int tiles = (N + 63) / 64;
  k_gn<16><<<NG, 256, 0, stream>>>(x, hA, goff, gn0_w, gn0_b, gn0_ms);
  k_conv<16><<<tiles, 256, 0, stream>>>(hA, hB, rowptr, col, w1_rel, b1, w1_root, N);
  k_gn<64><<<NG, 256, 0, stream>>>(hB, hB, goff, gn1_w, gn1_b, gn1_ms);
  k_conv<64><<<tiles, 256, 0, stream>>>(hB, hA, rowptr, col, w2_rel, b2, w2_root, N);
  k_gn<64><<<NG, 256, 0, stream>>>(hA, hA, goff, gn2_w, gn2_b, gn2_ms);
  k_conv<64><<<tiles, 256, 0, stream>>>(hA, hB, rowptr, col, w3_rel, b3, w3_root, N);
  k_final<<<NG, 256, 0, stream>>>(hB, goff, dense_w, dense_b, out_w, out_b, (float*)d_out);
}